// Round 8
// baseline (159.547 us; speedup 1.0000x reference)
//
#include <hip/hip_runtime.h>

#define CCH 16
#define DD 64
#define HH 96
#define WW 96
#define HW (HH*WW)
#define DHW (DD*HH*WW)   // 589824
#define CH4 (DHW/4)      // 147456
#define NTH 768          // 16 lh x 48 lc, 2 w-sites per thread
#define DCH 16           // depth outputs per block
#define NBY (DD/DCH)     // 4 depth chunks
#define KTR 1.08f        // 27 * k_harris (S unscaled by 1/27; ranking-invariant)
#define INV27C (1.f/19683.f)

// DPP row16 shifts: thread layout is lh-fast (lh = tid & 15), so a DPP row of
// 16 lanes == one h-column; bound_ctrl=true zero-fills at row ends (filled
// sites only feed masked-out outputs). Harris is invariant to an up/down swap.
__device__ __forceinline__ float dpp_up(float v) {
    return __int_as_float(__builtin_amdgcn_update_dpp(
        0, __float_as_int(v), 0x111 /*row_shr:1*/, 0xF, 0xF, true));
}
__device__ __forceinline__ float dpp_dn(float v) {
    return __int_as_float(__builtin_amdgcn_update_dpp(
        0, __float_as_int(v), 0x101 /*row_shl:1*/, 0xF, 0xF, true));
}

// R19: R15's exact skeleton (full unroll, per-slice VMEM fences, prefetch,
// (768,6) = the proven 85-VGPR budget) with a PURE-SCALAR body.
// Rationale: R11..R18 established dur = (VALU issue work) / (~50% hard cap):
// the cap survives LDS-vs-recompute, occupancy 24->30 waves, body 36->20 KB.
// Remaining levers are instruction COUNT and instruction BYTES. The v2f
// ext-vector machinery is the suspect for the measured ~330 instr/slice vs
// ~200 necessary: pair-builds {a,b}, cross-extractions {A.y,B.x} and
// broadcast-mask pk-muls emit v_movs (VOP3P needs adjacent aligned pairs) or
// scalarize anyway -- and VOP3P/DPP are 8-byte encodings vs 4-byte VOP2.
// Pure scalar: ~200 VALU/slice, mostly 4-byte v_add/v_mul/v_fmac + 48 DPP.
// Scalars also drop VGPR pressure (no pair-alignment) -> low spill risk.
struct Sl { float lx, ly, cx, cy, rx, ry; };

__global__ __launch_bounds__(NTH, 6)
void harris_sum_kernel(const float* __restrict__ x, float* __restrict__ pp) {
    __shared__ float red[12];

    const int tid = threadIdx.x;
    const int lh = tid & 15, lc = tid >> 4;   // lc 0..47
    const int c  = blockIdx.z;
    const int H0 = blockIdx.x * 12;
    const int o0 = blockIdx.y * DCH;
    const int gh = H0 + lh - 2;
    const bool rowok = ((unsigned)gh < HH);
    const bool lok = (lc > 0), rok = (lc < 47);
    const float mask  = rowok ? 1.f : 0.f;           // gradient row mask
    const float maskl = (rowok && lok) ? 1.f : 0.f;  // halo-site masks
    const float maskr = (rowok && rok) ? 1.f : 0.f;
    const float em = (lh >= 2 && lh <= 13) ? 1.f : 0.f;

    const int ghc   = min(max(gh, 0), HH - 1);       // row-clamped: always-valid addr
    const int woffc = ghc * WW + (lc << 1);
    const int woffl = lok ? woffc - 2 : woffc;       // w-halo offsets, edge-clamped
    const int woffr = rok ? woffc + 2 : woffc;
    const float* xc = x + (size_t)c * DHW;

    Sl p, m, n, f;

    auto loadslice = [&](int e, Sl& s) {
        const int ec = min(max(e, 0), DD - 1);       // depth-clamped (uniform SALU)
        const float* sp = xc + (size_t)(ec * HW);
        float2 tc = *(const float2*)(sp + woffc);
        float2 tl = *(const float2*)(sp + woffl);
        float2 tr2 = *(const float2*)(sp + woffr);
        if (e != ec) {                               // uniform branch (edge chunks only)
            tc = make_float2(0.f, 0.f); tl = make_float2(0.f, 0.f); tr2 = make_float2(0.f, 0.f);
        }
        s.lx = tl.x * maskl;  s.ly = tl.y * maskl;   // row/edge zero-pad, scalar muls
        s.cx = tc.x * mask;   s.cy = tc.y * mask;
        s.rx = tr2.x * maskr; s.ry = tr2.y * maskr;
    };

    loadslice(o0 - 2, p);
    loadslice(o0 - 1, m);
    loadslice(o0,     n);

    float s2m1[12], s2m2[12];
    #pragma unroll
    for (int i = 0; i < 12; ++i) { s2m1[i] = 0.f; s2m2[i] = 0.f; }
    float hv0 = 0.f, hv1 = 0.f;

    #pragma unroll
    for (int k = 0; k < DCH + 2; ++k) {       // 18 slices -> 16 output slices
        const int e = o0 - 1 + k;

        // prefetch slice e+2 (consumed next iteration)
        f.lx = f.ly = f.cx = f.cy = f.rx = f.ry = 0.f;
        if (k < DCH + 1) loadslice(e + 2, f);

        // depth [1,1,1] and [-1,0,1] windows (scalar)
        const float AL0 = (p.lx + m.lx) + n.lx, AL1 = (p.ly + m.ly) + n.ly;
        const float AC0 = (p.cx + m.cx) + n.cx, AC1 = (p.cy + m.cy) + n.cy;
        const float AR0 = (p.rx + m.rx) + n.rx, AR1 = (p.ry + m.ry) + n.ry;
        const float DL0 = n.lx - p.lx, DL1 = n.ly - p.ly;
        const float DC0 = n.cx - p.cx, DC1 = n.cy - p.cy;
        const float DR0 = n.rx - p.rx, DR1 = n.ry - p.ry;

        // w-convs at sites l, 0, 1, r
        const float Sxl = AC0 - AL0, Sx0 = AC1 - AL1;
        const float Sx1 = AR0 - AC0, Sxr = AR1 - AC1;
        const float Txl = fmaf(2.f, AL1, AL0 + AC0), Tx0 = fmaf(2.f, AC0, AL1 + AC1);
        const float Tx1 = fmaf(2.f, AC1, AC0 + AR0), Txr = fmaf(2.f, AR0, AC1 + AR1);
        const float a_ = DL1 + DC0, b_ = DC1 + DR0;
        const float Tdl = DL0 + a_, Td0 = a_ + DC1;
        const float Td1 = DC0 + b_, Tdr = b_ + DR1;

        // h-convs via DPP; paired-add form -> folds into v_add_f32_dpp
        #define HX(S)  ((dpp_up(S) + (S)) + (dpp_dn(S) + (S)))
        #define HY(T)  (dpp_dn(T) - dpp_up(T))
        #define HZ(T)  ((dpp_up(T) + (T)) + dpp_dn(T))
        const float glx = HX(Sxl) * maskl;
        const float gx0 = HX(Sx0) * mask;
        const float gx1 = HX(Sx1) * mask;
        const float grx = HX(Sxr) * maskr;
        const float gly = HY(Txl) * maskl;
        const float gy0 = HY(Tx0) * mask;
        const float gy1 = HY(Tx1) * mask;
        const float gry = HY(Txr) * maskr;
        const float glz = HZ(Tdl) * maskl;
        const float gz0 = HZ(Td0) * mask;
        const float gz1 = HZ(Td1) * mask;
        const float grz = HZ(Tdr) * maskr;

        // 6 fields: products -> w [1,1,1] -> h [1,1,1] via fused-DPP adds
        float s2c[12];
        #define FIELD(fi, Pl, P0, P1, Pr)                              \
        {   const float s_ = (P0) + (P1);                              \
            const float R0 = (Pl) + s_, R1 = s_ + (Pr);                \
            s2c[2*(fi)]   = (dpp_up(R0) + R0) + dpp_dn(R0);            \
            s2c[2*(fi)+1] = (dpp_up(R1) + R1) + dpp_dn(R1); }
        FIELD(0, glx*glx, gx0*gx0, gx1*gx1, grx*grx)
        FIELD(1, gly*gly, gy0*gy0, gy1*gy1, gry*gry)
        FIELD(2, glz*glz, gz0*gz0, gz1*gz1, grz*grz)
        FIELD(3, glx*gly, gx0*gy0, gx1*gy1, grx*gry)
        FIELD(4, glx*glz, gx0*gz0, gx1*gz1, grx*grz)
        FIELD(5, gly*glz, gy0*gz0, gy1*gz1, gry*grz)
        #undef FIELD
        #undef HX
        #undef HY
        #undef HZ

        if (k >= 2) {   // compile-time under full unroll; emit slice o = e-1
            const float sxx0 = (s2m2[0] + s2m1[0]) + s2c[0], sxx1 = (s2m2[1] + s2m1[1]) + s2c[1];
            const float syy0 = (s2m2[2] + s2m1[2]) + s2c[2], syy1 = (s2m2[3] + s2m1[3]) + s2c[3];
            const float szz0 = (s2m2[4] + s2m1[4]) + s2c[4], szz1 = (s2m2[5] + s2m1[5]) + s2c[5];
            const float sxy0 = (s2m2[6] + s2m1[6]) + s2c[6], sxy1 = (s2m2[7] + s2m1[7]) + s2c[7];
            const float sxz0 = (s2m2[8] + s2m1[8]) + s2c[8], sxz1 = (s2m2[9] + s2m1[9]) + s2c[9];
            const float syz0 = (s2m2[10] + s2m1[10]) + s2c[10], syz1 = (s2m2[11] + s2m1[11]) + s2c[11];

            const float u0 = fmaf(-syz0, syz0, syy0 * szz0);
            const float v0 = fmaf(-syz0, sxz0, sxy0 * szz0);
            const float w0 = fmaf(-syy0, sxz0, sxy0 * syz0);
            float det0 = sxx0 * u0;
            det0 = fmaf(-sxy0, v0, det0);
            det0 = fmaf(sxz0, w0, det0);
            const float tr0 = (sxx0 + syy0) + szz0;
            hv0 += fmaf(-KTR, tr0 * tr0, det0);

            const float u1 = fmaf(-syz1, syz1, syy1 * szz1);
            const float v1 = fmaf(-syz1, sxz1, sxy1 * szz1);
            const float w1 = fmaf(-syy1, sxz1, sxy1 * syz1);
            float det1 = sxx1 * u1;
            det1 = fmaf(-sxy1, v1, det1);
            det1 = fmaf(sxz1, w1, det1);
            const float tr1 = (sxx1 + syy1) + szz1;
            hv1 += fmaf(-KTR, tr1 * tr1, det1);
        }
        #pragma unroll
        for (int i = 0; i < 12; ++i) { s2m2[i] = s2m1[i]; s2m1[i] = s2c[i]; }
        p = m; m = n; n = f;

        // fence: ALU(0x1)|VALU(0x2)|SALU(0x4) may cross; VMEM/DS pinned to
        // their slice -> no cross-slice load hoisting (the R13/R14/R17 spill cause)
        __builtin_amdgcn_sched_barrier(0x7);
    }

    // non-emitted rows (lh<2 || lh>13) computed finite garbage; zero it here
    float hs = (hv0 + hv1) * em;
    // block reduce -> per-block partial slot (no atomics, no ws init needed)
    #pragma unroll
    for (int o = 32; o > 0; o >>= 1) hs += __shfl_down(hs, o, 64);
    if ((tid & 63) == 0) red[tid >> 6] = hs;
    __syncthreads();
    if (tid == 0) {
        float s = 0.f;
        #pragma unroll
        for (int i = 0; i < 12; ++i) s += red[i];
        pp[c * 32 + blockIdx.y * 8 + blockIdx.x] = s * INV27C;
    }
}

// Fused select+gather: every block recomputes the top-8 selection from pp
// (16x32 L2-hit loads + parallel rank -- cheaper than a separate kernel
// launch), then streams its copy tile. Summation order and rank tiebreak are
// fixed -> same selection in every block, deterministic.
__global__ __launch_bounds__(256)
void gather_topk_kernel(const float* __restrict__ x, const float* __restrict__ pp,
                        float4* __restrict__ out) {
    __shared__ float pv[CCH];
    __shared__ int sidx[8];
    const int tid = threadIdx.x;
    if (tid < CCH) {
        float s = 0.f;
        #pragma unroll
        for (int j = 0; j < 32; ++j) s += pp[tid * 32 + j];
        pv[tid] = s;   // fixed order -> deterministic across blocks
    }
    __syncthreads();
    if (tid < CCH) {
        const float v = pv[tid];
        int r = 0;
        #pragma unroll
        for (int i = 0; i < CCH; ++i) {
            const float u = pv[i];
            r += (u > v) || (u == v && i < tid);
        }
        if (r < 8) sidx[r] = tid;
    }
    __syncthreads();
    const int j = blockIdx.y;                        // 0..7
    const int cidx = sidx[j];                        // uniform
    const float4* src = (const float4*)(x + (size_t)cidx * DHW);
    float4* dst = out + (size_t)j * CH4;
    const int base = blockIdx.x * 1024 + tid;        // 144*1024 == CH4 exact
    #pragma unroll
    for (int t = 0; t < 4; ++t)
        dst[base + t * 256] = src[base + t * 256];
}

extern "C" void kernel_launch(void* const* d_in, const int* in_sizes, int n_in,
                              void* d_out, int out_size, void* d_ws, size_t ws_size,
                              hipStream_t stream) {
    const float* x = (const float*)d_in[0];
    float4* out = reinterpret_cast<float4*>(d_out);
    float* pp = (float*)d_ws;                        // 512 per-block partials (2 KB)

    dim3 g1(8, NBY, CCH);                            // (8,4,16) = 512 blocks
    harris_sum_kernel<<<g1, NTH, 0, stream>>>(x, pp);

    dim3 g2(CH4 / 1024, 8, 1);                       // (144, 8)
    gather_topk_kernel<<<g2, 256, 0, stream>>>(x, pp, out);
}

// Round 11
// 127.672 us; speedup vs baseline: 1.2497x; 1.2497x over previous
//
#include <hip/hip_runtime.h>

#define CCH 16
#define DD 64
#define HH 96
#define WW 96
#define HW (HH*WW)
#define DHW (DD*HH*WW)   // 589824
#define CH4 (DHW/4)      // 147456
#define NTH 768          // 16 lh x 48 lc, 2 w-sites per thread
#define DCH 16           // depth outputs per block
#define NBY (DD/DCH)     // 4 depth chunks
#define KTR 1.08f        // 27 * k_harris (S unscaled by 1/27; ranking-invariant)
#define INV27C (1.f/19683.f)

typedef float v2f __attribute__((ext_vector_type(2)));

// DPP row16 shifts: thread layout is lh-fast (lh = tid & 15), so a DPP row of
// 16 lanes == one h-column; bound_ctrl=true zero-fills at row ends (filled
// sites only feed masked-out outputs). Harris is invariant to an up/down swap.
__device__ __forceinline__ float dpp_up(float v) {
    return __int_as_float(__builtin_amdgcn_update_dpp(
        0, __float_as_int(v), 0x111 /*row_shr:1*/, 0xF, 0xF, true));
}
__device__ __forceinline__ float dpp_dn(float v) {
    return __int_as_float(__builtin_amdgcn_update_dpp(
        0, __float_as_int(v), 0x101 /*row_shl:1*/, 0xF, 0xF, true));
}

// R22 == R4 (the measured session best: 126.13 us total, passing, absmax 0).
// Harris body is the R15 allocator-stable shape: full unroll, branchless
// per-lane loads (clamped offsets + mask muls), 1-slice prefetch, per-slice
// sched_barrier(0x7) (VMEM pinned -> no cross-slice hoisting/spill), packed
// v2f math, fused-DPP h-convs, emit mask deferred to the end. Every body or
// bounds perturbation since (R13/R14/R16/R17/R19) spilled to scratch
// (WRITE_SIZE 14-543 MB); both single-kernel fusions (R20 spin barrier, R21
// cooperative) failed in this harness. This config is the converged optimum
// for the session.
__global__ __launch_bounds__(NTH, 6)
void harris_sum_kernel(const float* __restrict__ x, float* __restrict__ pp) {
    __shared__ float red[12];

    const int tid = threadIdx.x;
    const int lh = tid & 15, lc = tid >> 4;   // lc 0..47
    const int c  = blockIdx.z;
    const int H0 = blockIdx.x * 12;
    const int o0 = blockIdx.y * DCH;
    const int gh = H0 + lh - 2;
    const bool rowok = ((unsigned)gh < HH);
    const bool lok = (lc > 0), rok = (lc < 47);
    const float mask  = rowok ? 1.f : 0.f;           // gradient row mask
    const float maskl = (rowok && lok) ? 1.f : 0.f;  // halo-site masks
    const float maskr = (rowok && rok) ? 1.f : 0.f;
    const float em = (lh >= 2 && lh <= 13) ? 1.f : 0.f;

    const int ghc   = min(max(gh, 0), HH - 1);       // row-clamped: always-valid addr
    const int woffc = ghc * WW + (lc << 1);
    const int woffl = lok ? woffc - 2 : woffc;       // w-halo offsets, edge-clamped
    const int woffr = rok ? woffc + 2 : woffc;
    const float* xc = x + (size_t)c * DHW;

    // x window: slices e-1(p), e(m), e+1(n), in-flight (f); L/C/R = x[w-2..w+3]
    v2f Lp,Cp,Rp, Lm,Cm,Rm, Ln,Cn,Rn;

    auto loadslice = [&](int e, v2f& L, v2f& C, v2f& R) {
        const int ec = min(max(e, 0), DD - 1);       // depth-clamped (uniform SALU)
        const float* sp = xc + (size_t)(ec * HW);
        C = *(const v2f*)(sp + woffc);
        L = *(const v2f*)(sp + woffl);
        R = *(const v2f*)(sp + woffr);
        if (e != ec) {                               // uniform branch (edge chunks only)
            L = (v2f){0.f,0.f}; C = (v2f){0.f,0.f}; R = (v2f){0.f,0.f};
        }
        // row/edge zero-pad (broadcast-scalar pk muls)
        L *= (v2f){maskl, maskl};
        C *= (v2f){mask,  mask};
        R *= (v2f){maskr, maskr};
    };

    loadslice(o0 - 2, Lp, Cp, Rp);
    loadslice(o0 - 1, Lm, Cm, Rm);
    loadslice(o0,     Ln, Cn, Rn);

    v2f s2m1[6], s2m2[6];
    #pragma unroll
    for (int f = 0; f < 6; ++f) {
        s2m1[f] = (v2f){0.f,0.f};
        s2m2[f] = (v2f){0.f,0.f};
    }
    v2f hv = {0.f, 0.f};

    #pragma unroll
    for (int k = 0; k < DCH + 2; ++k) {       // 18 slices -> 16 output slices
        const int e = o0 - 1 + k;

        // prefetch slice e+2 (consumed next iteration; vmcnt(3) wait pattern)
        v2f Lf = {0.f,0.f}, Cf = {0.f,0.f}, Rf = {0.f,0.f};
        if (k < DCH + 1) loadslice(e + 2, Lf, Cf, Rf);

        // depth window (pk)
        const v2f AL = (Lp + Lm) + Ln;
        const v2f AC = (Cp + Cm) + Cn;
        const v2f AR = (Rp + Rm) + Rn;
        const v2f DL = Ln - Lp;
        const v2f DC = Cn - Cp;
        const v2f DR = Rn - Rp;

        // w-convs at sites l,0,1,r
        const v2f SxA = AC - AL;              // {Sxl, Sx0}  pk
        const v2f SxB = AR - AC;              // {Sx1, Sxr}  pk
        const float Txl = fmaf(2.f, AL.y, AL.x + AC.x);
        const float Tx0 = fmaf(2.f, AC.x, AL.y + AC.y);
        const float Tx1 = fmaf(2.f, AC.y, AC.x + AR.x);
        const float Txr = fmaf(2.f, AR.x, AC.y + AR.y);
        const float p01 = DL.y + DC.x, p23 = DC.y + DR.x;
        const float Tdl = DL.x + p01,  Td0 = p01 + DC.y;
        const float Td1 = DC.x + p23,  Tdr = p23 + DR.y;

        // h-convs via DPP; paired-add form -> folds into v_add_f32_dpp
        #define HX(S)  ((dpp_up(S) + (S)) + (dpp_dn(S) + (S)))
        #define HY(T)  (dpp_dn(T) - dpp_up(T))
        #define HZ(T)  ((dpp_up(T) + (T)) + dpp_dn(T))
        v2f gxA = {HX(SxA.x), HX(SxA.y)};  gxA *= (v2f){maskl, mask};   // {glx, gx0}
        v2f gxB = {HX(SxB.x), HX(SxB.y)};  gxB *= (v2f){mask, maskr};   // {gx1, grx}
        v2f gyA = {HY(Txl),   HY(Tx0)};    gyA *= (v2f){maskl, mask};
        v2f gyB = {HY(Tx1),   HY(Txr)};    gyB *= (v2f){mask, maskr};
        v2f gzA = {HZ(Tdl),   HZ(Td0)};    gzA *= (v2f){maskl, mask};
        v2f gzB = {HZ(Td1),   HZ(Tdr)};    gzB *= (v2f){mask, maskr};

        // products: own pair {g0,g1} packed; halo pair {gl,gr} packed
        const v2f gx0v = {gxA.y, gxB.x}, gy0v = {gyA.y, gyB.x}, gz0v = {gzA.y, gzB.x};
        const v2f gxh  = {gxA.x, gxB.y}, gyh  = {gyA.x, gyB.y}, gzh  = {gzA.x, gzB.y};
        const v2f Pxx = gx0v*gx0v, Pyy = gy0v*gy0v, Pzz = gz0v*gz0v;
        const v2f Pxy = gx0v*gy0v, Pxz = gx0v*gz0v, Pyz = gy0v*gz0v;
        const v2f Phxx = gxh*gxh, Phyy = gyh*gyh, Phzz = gzh*gzh;
        const v2f Phxy = gxh*gyh, Phxz = gxh*gzh, Phyz = gyh*gzh;

        // w [1,1,1] on products + h [1,1,1] via fused-DPP adds
        v2f s2c[6];
        #define FIELD(f, Pv, Ph)                                       \
        {   const float s_ = (Pv).x + (Pv).y;                          \
            const v2f Rv = (Ph) + (v2f){s_, s_};                       \
            s2c[f].x = HZ(Rv.x);                                       \
            s2c[f].y = HZ(Rv.y); }
        FIELD(0, Pxx, Phxx)
        FIELD(1, Pyy, Phyy)
        FIELD(2, Pzz, Phzz)
        FIELD(3, Pxy, Phxy)
        FIELD(4, Pxz, Phxz)
        FIELD(5, Pyz, Phyz)
        #undef FIELD
        #undef HX
        #undef HY
        #undef HZ

        if (k >= 2) {   // compile-time under full unroll; emit slice o = e-1
            const v2f sxx = (s2m2[0] + s2m1[0]) + s2c[0];
            const v2f syy = (s2m2[1] + s2m1[1]) + s2c[1];
            const v2f szz = (s2m2[2] + s2m1[2]) + s2c[2];
            const v2f sxy = (s2m2[3] + s2m1[3]) + s2c[3];
            const v2f sxz = (s2m2[4] + s2m1[4]) + s2c[4];
            const v2f syz = (s2m2[5] + s2m1[5]) + s2c[5];
            const v2f det = sxx*(syy*szz - syz*syz)
                          - sxy*(sxy*szz - syz*sxz)
                          + sxz*(sxy*syz - syy*sxz);
            const v2f tr = (sxx + syy) + szz;
            hv += det - KTR*(tr*tr);   // emit-row mask deferred to the end
        }
        #pragma unroll
        for (int f = 0; f < 6; ++f) { s2m2[f] = s2m1[f]; s2m1[f] = s2c[f]; }
        Lp = Lm; Cp = Cm; Rp = Rm;
        Lm = Ln; Cm = Cn; Rm = Rn;
        Ln = Lf; Cn = Cf; Rn = Rf;

        // fence: ALU(0x1)|VALU(0x2)|SALU(0x4) may cross; VMEM/DS pinned to
        // their slice -> no cross-slice load hoisting (the spill cause)
        __builtin_amdgcn_sched_barrier(0x7);
    }

    // non-emitted rows (lh<2 || lh>13) computed finite garbage; zero it here
    float hs = (hv.x + hv.y) * em;
    // block reduce -> per-block partial slot (no atomics, no ws init needed)
    #pragma unroll
    for (int o = 32; o > 0; o >>= 1) hs += __shfl_down(hs, o, 64);
    if ((tid & 63) == 0) red[tid >> 6] = hs;
    __syncthreads();
    if (tid == 0) {
        float s = 0.f;
        #pragma unroll
        for (int i = 0; i < 12; ++i) s += red[i];
        pp[c * 32 + blockIdx.y * 8 + blockIdx.x] = s * INV27C;
    }
}

// Fused select+gather: every block recomputes the top-8 selection from pp
// (16x32 L2-hit loads + parallel rank -- cheaper than a separate kernel
// launch), then streams its copy tile. Summation order and rank tiebreak are
// fixed -> same selection in every block, deterministic.
__global__ __launch_bounds__(256)
void gather_topk_kernel(const float* __restrict__ x, const float* __restrict__ pp,
                        float4* __restrict__ out) {
    __shared__ float pv[CCH];
    __shared__ int sidx[8];
    const int tid = threadIdx.x;
    if (tid < CCH) {
        float s = 0.f;
        #pragma unroll
        for (int j = 0; j < 32; ++j) s += pp[tid * 32 + j];
        pv[tid] = s;   // fixed order -> deterministic across blocks
    }
    __syncthreads();
    if (tid < CCH) {
        const float v = pv[tid];
        int r = 0;
        #pragma unroll
        for (int i = 0; i < CCH; ++i) {
            const float u = pv[i];
            r += (u > v) || (u == v && i < tid);
        }
        if (r < 8) sidx[r] = tid;
    }
    __syncthreads();
    const int j = blockIdx.y;                        // 0..7
    const int cidx = sidx[j];                        // uniform
    const float4* src = (const float4*)(x + (size_t)cidx * DHW);
    float4* dst = out + (size_t)j * CH4;
    const int base = blockIdx.x * 1024 + tid;        // 144*1024 == CH4 exact
    #pragma unroll
    for (int t = 0; t < 4; ++t)
        dst[base + t * 256] = src[base + t * 256];
}

extern "C" void kernel_launch(void* const* d_in, const int* in_sizes, int n_in,
                              void* d_out, int out_size, void* d_ws, size_t ws_size,
                              hipStream_t stream) {
    const float* x = (const float*)d_in[0];
    float4* out = reinterpret_cast<float4*>(d_out);
    float* pp = (float*)d_ws;                        // 512 per-block partials (2 KB)

    dim3 g1(8, NBY, CCH);                            // (8,4,16) = 512 blocks
    harris_sum_kernel<<<g1, NTH, 0, stream>>>(x, pp);

    dim3 g2(CH4 / 1024, 8, 1);                       // (144, 8)
    gather_topk_kernel<<<g2, 256, 0, stream>>>(x, pp, out);
}

// Round 13
// 126.078 us; speedup vs baseline: 1.2655x; 1.0126x over previous
//
#include <hip/hip_runtime.h>

#define CCH 16
#define DD 64
#define HH 96
#define WW 96
#define HW (HH*WW)
#define DHW (DD*HH*WW)   // 589824
#define CH4 (DHW/4)      // 147456
#define NTH 768          // 16 lh x 48 lc, 2 w-sites per thread
#define DCH 16           // depth outputs per block
#define NBY (DD/DCH)     // 4 depth chunks
#define KTR 1.08f        // 27 * k_harris (S unscaled by 1/27; ranking-invariant)
#define INV27C (1.f/19683.f)

typedef float v2f __attribute__((ext_vector_type(2)));

// DPP row16 shifts: thread layout is lh-fast (lh = tid & 15), so a DPP row of
// 16 lanes == one h-column; bound_ctrl=true zero-fills at row ends (filled
// sites only feed masked-out outputs). Harris is invariant to an up/down swap.
__device__ __forceinline__ float dpp_up(float v) {
    return __int_as_float(__builtin_amdgcn_update_dpp(
        0, __float_as_int(v), 0x111 /*row_shr:1*/, 0xF, 0xF, true));
}
__device__ __forceinline__ float dpp_dn(float v) {
    return __int_as_float(__builtin_amdgcn_update_dpp(
        0, __float_as_int(v), 0x101 /*row_shl:1*/, 0xF, 0xF, true));
}

// R24 (FINAL) == R22 == R4: the twice-verified session best (126.1 / 127.7 us,
// passing, absmax 0.0). Harris body is the allocator-stable R15 shape: full
// unroll, branchless clamped-offset loads + mask muls, 1-slice prefetch,
// per-slice sched_barrier(0x7) (VMEM pinned per slice -> no cross-slice
// hoisting -> no spill; R13/R14/R16/R17/R19 all spilled on perturbation),
// packed v2f math, fused-DPP h-convs, deferred emit mask.
// Tail: fused select+gather in a second kernel. Single-kernel fusion was
// attempted 3x and fails under this harness (R20 spin barrier: hang at exact
// capacity; R21 cooperative launch: silent no-launch; R23 last-arrivers:
// re-poison race via epoch-counter overflow). Two kernels is the robust
// optimum here.
__global__ __launch_bounds__(NTH, 6)
void harris_sum_kernel(const float* __restrict__ x, float* __restrict__ pp) {
    __shared__ float red[12];

    const int tid = threadIdx.x;
    const int lh = tid & 15, lc = tid >> 4;   // lc 0..47
    const int c  = blockIdx.z;
    const int H0 = blockIdx.x * 12;
    const int o0 = blockIdx.y * DCH;
    const int gh = H0 + lh - 2;
    const bool rowok = ((unsigned)gh < HH);
    const bool lok = (lc > 0), rok = (lc < 47);
    const float mask  = rowok ? 1.f : 0.f;           // gradient row mask
    const float maskl = (rowok && lok) ? 1.f : 0.f;  // halo-site masks
    const float maskr = (rowok && rok) ? 1.f : 0.f;
    const float em = (lh >= 2 && lh <= 13) ? 1.f : 0.f;

    const int ghc   = min(max(gh, 0), HH - 1);       // row-clamped: always-valid addr
    const int woffc = ghc * WW + (lc << 1);
    const int woffl = lok ? woffc - 2 : woffc;       // w-halo offsets, edge-clamped
    const int woffr = rok ? woffc + 2 : woffc;
    const float* xc = x + (size_t)c * DHW;

    // x window: slices e-1(p), e(m), e+1(n), in-flight (f); L/C/R = x[w-2..w+3]
    v2f Lp,Cp,Rp, Lm,Cm,Rm, Ln,Cn,Rn;

    auto loadslice = [&](int e, v2f& L, v2f& C, v2f& R) {
        const int ec = min(max(e, 0), DD - 1);       // depth-clamped (uniform SALU)
        const float* sp = xc + (size_t)(ec * HW);
        C = *(const v2f*)(sp + woffc);
        L = *(const v2f*)(sp + woffl);
        R = *(const v2f*)(sp + woffr);
        if (e != ec) {                               // uniform branch (edge chunks only)
            L = (v2f){0.f,0.f}; C = (v2f){0.f,0.f}; R = (v2f){0.f,0.f};
        }
        // row/edge zero-pad (broadcast-scalar pk muls)
        L *= (v2f){maskl, maskl};
        C *= (v2f){mask,  mask};
        R *= (v2f){maskr, maskr};
    };

    loadslice(o0 - 2, Lp, Cp, Rp);
    loadslice(o0 - 1, Lm, Cm, Rm);
    loadslice(o0,     Ln, Cn, Rn);

    v2f s2m1[6], s2m2[6];
    #pragma unroll
    for (int f = 0; f < 6; ++f) {
        s2m1[f] = (v2f){0.f,0.f};
        s2m2[f] = (v2f){0.f,0.f};
    }
    v2f hv = {0.f, 0.f};

    #pragma unroll
    for (int k = 0; k < DCH + 2; ++k) {       // 18 slices -> 16 output slices
        const int e = o0 - 1 + k;

        // prefetch slice e+2 (consumed next iteration; vmcnt(3) wait pattern)
        v2f Lf = {0.f,0.f}, Cf = {0.f,0.f}, Rf = {0.f,0.f};
        if (k < DCH + 1) loadslice(e + 2, Lf, Cf, Rf);

        // depth window (pk)
        const v2f AL = (Lp + Lm) + Ln;
        const v2f AC = (Cp + Cm) + Cn;
        const v2f AR = (Rp + Rm) + Rn;
        const v2f DL = Ln - Lp;
        const v2f DC = Cn - Cp;
        const v2f DR = Rn - Rp;

        // w-convs at sites l,0,1,r
        const v2f SxA = AC - AL;              // {Sxl, Sx0}  pk
        const v2f SxB = AR - AC;              // {Sx1, Sxr}  pk
        const float Txl = fmaf(2.f, AL.y, AL.x + AC.x);
        const float Tx0 = fmaf(2.f, AC.x, AL.y + AC.y);
        const float Tx1 = fmaf(2.f, AC.y, AC.x + AR.x);
        const float Txr = fmaf(2.f, AR.x, AC.y + AR.y);
        const float p01 = DL.y + DC.x, p23 = DC.y + DR.x;
        const float Tdl = DL.x + p01,  Td0 = p01 + DC.y;
        const float Td1 = DC.x + p23,  Tdr = p23 + DR.y;

        // h-convs via DPP; paired-add form -> folds into v_add_f32_dpp
        #define HX(S)  ((dpp_up(S) + (S)) + (dpp_dn(S) + (S)))
        #define HY(T)  (dpp_dn(T) - dpp_up(T))
        #define HZ(T)  ((dpp_up(T) + (T)) + dpp_dn(T))
        v2f gxA = {HX(SxA.x), HX(SxA.y)};  gxA *= (v2f){maskl, mask};   // {glx, gx0}
        v2f gxB = {HX(SxB.x), HX(SxB.y)};  gxB *= (v2f){mask, maskr};   // {gx1, grx}
        v2f gyA = {HY(Txl),   HY(Tx0)};    gyA *= (v2f){maskl, mask};
        v2f gyB = {HY(Tx1),   HY(Txr)};    gyB *= (v2f){mask, maskr};
        v2f gzA = {HZ(Tdl),   HZ(Td0)};    gzA *= (v2f){maskl, mask};
        v2f gzB = {HZ(Td1),   HZ(Tdr)};    gzB *= (v2f){mask, maskr};

        // products: own pair {g0,g1} packed; halo pair {gl,gr} packed
        const v2f gx0v = {gxA.y, gxB.x}, gy0v = {gyA.y, gyB.x}, gz0v = {gzA.y, gzB.x};
        const v2f gxh  = {gxA.x, gxB.y}, gyh  = {gyA.x, gyB.y}, gzh  = {gzA.x, gzB.y};
        const v2f Pxx = gx0v*gx0v, Pyy = gy0v*gy0v, Pzz = gz0v*gz0v;
        const v2f Pxy = gx0v*gy0v, Pxz = gx0v*gz0v, Pyz = gy0v*gz0v;
        const v2f Phxx = gxh*gxh, Phyy = gyh*gyh, Phzz = gzh*gzh;
        const v2f Phxy = gxh*gyh, Phxz = gxh*gzh, Phyz = gyh*gzh;

        // w [1,1,1] on products + h [1,1,1] via fused-DPP adds
        v2f s2c[6];
        #define FIELD(f, Pv, Ph)                                       \
        {   const float s_ = (Pv).x + (Pv).y;                          \
            const v2f Rv = (Ph) + (v2f){s_, s_};                       \
            s2c[f].x = HZ(Rv.x);                                       \
            s2c[f].y = HZ(Rv.y); }
        FIELD(0, Pxx, Phxx)
        FIELD(1, Pyy, Phyy)
        FIELD(2, Pzz, Phzz)
        FIELD(3, Pxy, Phxy)
        FIELD(4, Pxz, Phxz)
        FIELD(5, Pyz, Phyz)
        #undef FIELD
        #undef HX
        #undef HY
        #undef HZ

        if (k >= 2) {   // compile-time under full unroll; emit slice o = e-1
            const v2f sxx = (s2m2[0] + s2m1[0]) + s2c[0];
            const v2f syy = (s2m2[1] + s2m1[1]) + s2c[1];
            const v2f szz = (s2m2[2] + s2m1[2]) + s2c[2];
            const v2f sxy = (s2m2[3] + s2m1[3]) + s2c[3];
            const v2f sxz = (s2m2[4] + s2m1[4]) + s2c[4];
            const v2f syz = (s2m2[5] + s2m1[5]) + s2c[5];
            const v2f det = sxx*(syy*szz - syz*syz)
                          - sxy*(sxy*szz - syz*sxz)
                          + sxz*(sxy*syz - syy*sxz);
            const v2f tr = (sxx + syy) + szz;
            hv += det - KTR*(tr*tr);   // emit-row mask deferred to the end
        }
        #pragma unroll
        for (int f = 0; f < 6; ++f) { s2m2[f] = s2m1[f]; s2m1[f] = s2c[f]; }
        Lp = Lm; Cp = Cm; Rp = Rm;
        Lm = Ln; Cm = Cn; Rm = Rn;
        Ln = Lf; Cn = Cf; Rn = Rf;

        // fence: ALU(0x1)|VALU(0x2)|SALU(0x4) may cross; VMEM/DS pinned to
        // their slice -> no cross-slice load hoisting (the spill cause)
        __builtin_amdgcn_sched_barrier(0x7);
    }

    // non-emitted rows (lh<2 || lh>13) computed finite garbage; zero it here
    float hs = (hv.x + hv.y) * em;
    // block reduce -> per-block partial slot (no atomics, no ws init needed)
    #pragma unroll
    for (int o = 32; o > 0; o >>= 1) hs += __shfl_down(hs, o, 64);
    if ((tid & 63) == 0) red[tid >> 6] = hs;
    __syncthreads();
    if (tid == 0) {
        float s = 0.f;
        #pragma unroll
        for (int i = 0; i < 12; ++i) s += red[i];
        pp[c * 32 + blockIdx.y * 8 + blockIdx.x] = s * INV27C;
    }
}

// Fused select+gather: every block recomputes the top-8 selection from pp
// (16x32 L2-hit loads + parallel rank -- cheaper than a separate kernel
// launch), then streams its copy tile. Summation order and rank tiebreak are
// fixed -> same selection in every block, deterministic.
__global__ __launch_bounds__(256)
void gather_topk_kernel(const float* __restrict__ x, const float* __restrict__ pp,
                        float4* __restrict__ out) {
    __shared__ float pv[CCH];
    __shared__ int sidx[8];
    const int tid = threadIdx.x;
    if (tid < CCH) {
        float s = 0.f;
        #pragma unroll
        for (int j = 0; j < 32; ++j) s += pp[tid * 32 + j];
        pv[tid] = s;   // fixed order -> deterministic across blocks
    }
    __syncthreads();
    if (tid < CCH) {
        const float v = pv[tid];
        int r = 0;
        #pragma unroll
        for (int i = 0; i < CCH; ++i) {
            const float u = pv[i];
            r += (u > v) || (u == v && i < tid);
        }
        if (r < 8) sidx[r] = tid;
    }
    __syncthreads();
    const int j = blockIdx.y;                        // 0..7
    const int cidx = sidx[j];                        // uniform
    const float4* src = (const float4*)(x + (size_t)cidx * DHW);
    float4* dst = out + (size_t)j * CH4;
    const int base = blockIdx.x * 1024 + tid;        // 144*1024 == CH4 exact
    #pragma unroll
    for (int t = 0; t < 4; ++t)
        dst[base + t * 256] = src[base + t * 256];
}

extern "C" void kernel_launch(void* const* d_in, const int* in_sizes, int n_in,
                              void* d_out, int out_size, void* d_ws, size_t ws_size,
                              hipStream_t stream) {
    const float* x = (const float*)d_in[0];
    float4* out = reinterpret_cast<float4*>(d_out);
    float* pp = (float*)d_ws;                        // 512 per-block partials (2 KB)

    dim3 g1(8, NBY, CCH);                            // (8,4,16) = 512 blocks
    harris_sum_kernel<<<g1, NTH, 0, stream>>>(x, pp);

    dim3 g2(CH4 / 1024, 8, 1);                       // (144, 8)
    gather_topk_kernel<<<g2, 256, 0, stream>>>(x, pp, out);
}